// Round 11
// baseline (27.559 us; speedup 1.0000x reference)
//
#include <hip/hip_runtime.h>
#include <math.h>

typedef short bf16x8 __attribute__((ext_vector_type(8)));
typedef float f32x16 __attribute__((ext_vector_type(16)));
typedef unsigned int u32x4 __attribute__((ext_vector_type(4)));

#define B 16
#define N 4096
#define K 4096
#define OBJ_ELEMS (8*512*3)        // 12288 per batch
#define OBJ_VEC4  (OBJ_ELEMS/4)    // 3072 float4 per batch
#define NSEG 64
#define NCHUNK (N/NSEG)            // 64 adv rows per block (2 groups x 32)
#define BLK 256
#define OBJ_V4_PER_BLK (OBJ_VEC4/NSEG) // 48 float4 per block
#define CD_W 0.2f
#define EPS_F 1e-7f

// ws layout (floats): csum[B*NSEG] @0, lsq[B*NSEG] @1024, packed bf16 ori @2048
#define CS_OFF 0
#define LS_OFF (B*NSEG)
#define PK_OFF (2*B*NSEG)

__device__ __forceinline__ unsigned short f2bf(float f) {
    unsigned int u = __float_as_uint(f);
    u = (u + 0x7FFFu + ((u >> 16) & 1u)) >> 16;   // RNE
    return (unsigned short)u;
}

__global__ __launch_bounds__(256) void pack_ori_bf16_kernel(
    const float* __restrict__ ori, ushort4* __restrict__ packed)
{
    int i = blockIdx.x * 256 + threadIdx.x;   // [0, B*K)
    const float* s = ori + i*3;
    float x = s[0], y = s[1], z = s[2];
    float o2 = x*x + y*y + z*z;
    ushort4 u;
    u.x = f2bf(-2.f*x); u.y = f2bf(-2.f*y);
    u.z = f2bf(-2.f*z); u.w = f2bf(o2);
    packed[i] = u;
}

__global__ __launch_bounds__(BLK) void chamfer_mfma_kernel(
    const float* __restrict__ adv, const ushort4* __restrict__ packed,
    const float* __restrict__ adv_obj, const float* __restrict__ ori_obj,
    float* __restrict__ csum, float* __restrict__ lsq)
{
    __shared__ float4 slds[K/2];           // 32 KB: bf16 ori (2 pts / float4)
    __shared__ float  rowmin[4][32];       // per-wave row-mins
    __shared__ float  a2lds[NCHUNK];       // fp32 |a|^2 per row

    const int nseg = blockIdx.x;
    const int b    = blockIdx.y;
    const int tid  = threadIdx.x;
    const int wid  = tid >> 6;
    const int lane = tid & 63;
    const int col  = lane & 31;
    const int hi   = lane >> 5;
    const int rg   = wid & 1;              // row group (32 rows)
    const int kh   = wid >> 1;             // ori half (2048 points)

    // --- stage packed ori: pure float4 copy, 8 per thread ---
    const float4* src = reinterpret_cast<const float4*>(packed) + b*(K/2);
    #pragma unroll
    for (int i = 0; i < (K/2)/BLK; ++i)
        slds[tid + i*BLK] = src[tid + i*BLK];

    // --- A fragment: 32 adv rows of this row-group, K=4 in low half ---
    const int n = nseg*NCHUNK + rg*32 + col;
    const float* ap = adv + (b*N + n)*3;
    float ax = ap[0], ay = ap[1], az = ap[2];
    float a2 = ax*ax + ay*ay + az*az;
    if (kh == 0 && hi == 0) a2lds[rg*32 + col] = a2;
    bf16x8 afrag;
    if (hi == 0) {
        afrag[0] = (short)f2bf(ax);
        afrag[1] = (short)f2bf(ay);
        afrag[2] = (short)f2bf(az);
        afrag[3] = (short)0x3F80;          // bf16 1.0
    } else {
        afrag[0] = 0; afrag[1] = 0; afrag[2] = 0; afrag[3] = 0;
    }
    afrag[4] = 0; afrag[5] = 0; afrag[6] = 0; afrag[7] = 0;

    __syncthreads();

    // --- main loop: this wave's 64 ori tiles of 32 points ---
    f32x16 acc = {INFINITY,INFINITY,INFINITY,INFINITY,
                  INFINITY,INFINITY,INFINITY,INFINITY,
                  INFINITY,INFINITY,INFINITY,INFINITY,
                  INFINITY,INFINITY,INFINITY,INFINITY};
    const f32x16 zc = {0,0,0,0, 0,0,0,0, 0,0,0,0, 0,0,0,0};
    const uint2* s2 = reinterpret_cast<const uint2*>(slds);   // 1 pt / uint2

    #pragma unroll 4
    for (int t = kh*64; t < kh*64 + 64; t += 2) {
        uint2 q0 = s2[t*32 + col];
        uint2 q1 = s2[(t+1)*32 + col];
        u32x4 w0 = {q0.x, q0.y, 0u, 0u};
        u32x4 w1 = {q1.x, q1.y, 0u, 0u};
        bf16x8 b0 = __builtin_bit_cast(bf16x8, w0);
        bf16x8 b1 = __builtin_bit_cast(bf16x8, w1);
        f32x16 c0 = __builtin_amdgcn_mfma_f32_32x32x16_bf16(afrag, b0, zc, 0,0,0);
        f32x16 c1 = __builtin_amdgcn_mfma_f32_32x32x16_bf16(afrag, b1, zc, 0,0,0);
        #pragma unroll
        for (int r = 0; r < 16; ++r)
            acc[r] = fminf(fminf(c0[r], c1[r]), acc[r]);   // v_min3_f32
    }

    // --- col-min within each 32-lane half ---
    #pragma unroll
    for (int r = 0; r < 16; ++r) {
        float v = acc[r];
        v = fminf(v, __shfl_xor(v, 1));
        v = fminf(v, __shfl_xor(v, 2));
        v = fminf(v, __shfl_xor(v, 4));
        v = fminf(v, __shfl_xor(v, 8));
        v = fminf(v, __shfl_xor(v, 16));
        acc[r] = v;
    }
    if (col == 0) {   // lanes 0 and 32 publish 16 rows each
        #pragma unroll
        for (int r = 0; r < 16; ++r)
            rowmin[wid][(r&3) + 8*(r>>2) + 4*hi] = acc[r];
    }
    __syncthreads();

    // --- epilogue: combine ori halves, add a2, fold obj-L2 ---
    float s = 0.f;
    if (wid == 0) {            // 64 threads: one adv row each
        int rg2 = lane >> 5, row = lane & 31;
        float m = fminf(rowmin[rg2][row], rowmin[2 + rg2][row]);
        s = m + a2lds[lane];
    } else if (wid == 1) {     // 48 of 64 threads: obj-L2 slice
        if (lane < OBJ_V4_PER_BLK) {
            int idx = b*OBJ_VEC4 + nseg*OBJ_V4_PER_BLK + lane;
            float4 a = reinterpret_cast<const float4*>(adv_obj)[idx];
            float4 o = reinterpret_cast<const float4*>(ori_obj)[idx];
            float dx = a.x - o.x, dy = a.y - o.y, dz = a.z - o.z, dw = a.w - o.w;
            s = dx*dx + dy*dy + dz*dz + dw*dw;
        }
    }
    #pragma unroll
    for (int off = 32; off; off >>= 1) s += __shfl_down(s, off);
    if (wid == 0 && lane == 0) csum[b*NSEG + nseg] = s;
    if (wid == 1 && lane == 0) lsq [b*NSEG + nseg] = s;
}

__global__ __launch_bounds__(256) void final_kernel(
    const float* __restrict__ csum, const float* __restrict__ lsq,
    const float* __restrict__ w, float* __restrict__ out)
{
    const int tid = threadIdx.x;           // 256 threads x 4 partials each
    float c = 0.f, l = 0.f;
    #pragma unroll
    for (int j = 0; j < 4; ++j) {
        c += csum[4*tid + j];
        l += lsq [4*tid + j];
    }
    // 16 lanes per batch (16 x 4 = 64 partials)
    #pragma unroll
    for (int off = 8; off; off >>= 1) {
        c += __shfl_down(c, off, 16);
        l += __shfl_down(l, off, 16);
    }
    __shared__ float sc[B], sl[B];
    int bb = tid >> 4;
    if ((tid & 15) == 0) { sc[bb] = c; sl[bb] = l; }
    __syncthreads();
    if (tid < 64) {
        float cc = 0.f, ll = 0.f;
        if (tid < B) {
            float wt = w[tid];
            cc = (sc[tid] / (float)N) * wt;
            ll = sqrtf(sl[tid] + EPS_F) * wt;
        }
        #pragma unroll
        for (int off = 8; off; off >>= 1) {
            cc += __shfl_down(cc, off);
            ll += __shfl_down(ll, off);
        }
        if (tid == 0) out[0] = ll / (float)B + CD_W * (cc / (float)B);
    }
}

extern "C" void kernel_launch(void* const* d_in, const int* in_sizes, int n_in,
                              void* d_out, int out_size, void* d_ws, size_t ws_size,
                              hipStream_t stream)
{
    const float* adv_pc  = (const float*)d_in[0];
    const float* ori_pc  = (const float*)d_in[1];
    const float* adv_obj = (const float*)d_in[2];
    const float* ori_obj = (const float*)d_in[3];
    const float* weights = (const float*)d_in[4];
    float* out = (float*)d_out;
    float* ws  = (float*)d_ws;

    float*   csum   = ws + CS_OFF;
    float*   lsq    = ws + LS_OFF;
    ushort4* packed = (ushort4*)(ws + PK_OFF);

    // 1) pack ori -> bf16 {-2x,-2y,-2z,o2} once (256 blocks)
    pack_ori_bf16_kernel<<<dim3(B*K/256), dim3(256), 0, stream>>>(ori_pc, packed);

    // 2) fused MFMA chamfer + obj-L2 partials: grid = (NSEG, B) = 1024 blocks
    chamfer_mfma_kernel<<<dim3(NSEG, B), dim3(BLK), 0, stream>>>(
        adv_pc, packed, adv_obj, ori_obj, csum, lsq);

    // 3) weighted final combine (1 block)
    final_kernel<<<dim3(1), dim3(256), 0, stream>>>(csum, lsq, weights, out);
}

// Round 12
// 19.693 us; speedup vs baseline: 1.3994x; 1.3994x over previous
//
#include <hip/hip_runtime.h>
#include <math.h>

typedef short bf16x8 __attribute__((ext_vector_type(8)));
typedef float f32x16 __attribute__((ext_vector_type(16)));
typedef unsigned int u32x4 __attribute__((ext_vector_type(4)));

#define B 16
#define N 4096
#define K 4096
#define OBJ_ELEMS (8*512*3)        // 12288 per batch
#define OBJ_VEC4  (OBJ_ELEMS/4)    // 3072 float4 per batch
#define NSEG 32
#define NCHUNK (N/NSEG)            // 128 adv rows per block (4 groups x 32)
#define BLK 512                    // 8 waves: 4 row-groups x 2 K-halves
#define OBJ_V4_PER_BLK (OBJ_VEC4/NSEG) // 96 float4 per block
#define CD_W 0.2f
#define EPS_F 1e-7f

// ws layout (floats): csum[B*NSEG] @0, lsq[B*NSEG] @512
#define CS_OFF 0
#define LS_OFF (B*NSEG)

__device__ __forceinline__ unsigned short f2bf(float f) {
    unsigned int u = __float_as_uint(f);
    u = (u + 0x7FFFu + ((u >> 16) & 1u)) >> 16;   // RNE
    return (unsigned short)u;
}

__global__ __launch_bounds__(BLK) void chamfer_mfma_kernel(
    const float* __restrict__ adv, const float* __restrict__ ori,
    const float* __restrict__ adv_obj, const float* __restrict__ ori_obj,
    float* __restrict__ csum, float* __restrict__ lsq)
{
    __shared__ ushort4 slds[K];            // 32 KB: ori bf16 {-2x,-2y,-2z,o2}
    __shared__ float   rowmin[8][32];      // per-wave row-mins
    __shared__ float   a2lds[NCHUNK];      // fp32 |a|^2 per row
    __shared__ float   red_c[2], red_l[2];

    const int nseg = blockIdx.x;
    const int b    = blockIdx.y;
    const int tid  = threadIdx.x;
    const int wid  = tid >> 6;
    const int lane = tid & 63;
    const int col  = lane & 31;
    const int hi   = lane >> 5;
    const int rg   = wid & 3;              // row group (32 rows each)
    const int kh   = wid >> 2;             // K half (2048 ori points each)

    // --- stage + convert ori into LDS (8 points per thread, coalesced) ---
    #pragma unroll
    for (int i = 0; i < K/BLK; ++i) {
        int p = tid + i*BLK;
        const float* s = ori + (b*K + p)*3;
        float x = s[0], y = s[1], z = s[2];
        float o2 = x*x + y*y + z*z;
        ushort4 u;
        u.x = f2bf(-2.f*x); u.y = f2bf(-2.f*y);
        u.z = f2bf(-2.f*z); u.w = f2bf(o2);
        slds[p] = u;
    }

    // --- A fragment: this wave's 32 adv rows, K=4 in low half ---
    const int n = nseg*NCHUNK + rg*32 + col;
    const float* ap = adv + (b*N + n)*3;
    float ax = ap[0], ay = ap[1], az = ap[2];
    float a2 = ax*ax + ay*ay + az*az;
    if (kh == 0 && hi == 0) a2lds[rg*32 + col] = a2;
    bf16x8 afrag;
    if (hi == 0) {
        afrag[0] = (short)f2bf(ax);
        afrag[1] = (short)f2bf(ay);
        afrag[2] = (short)f2bf(az);
        afrag[3] = (short)0x3F80;          // bf16 1.0
    } else {
        afrag[0] = 0; afrag[1] = 0; afrag[2] = 0; afrag[3] = 0;
    }
    afrag[4] = 0; afrag[5] = 0; afrag[6] = 0; afrag[7] = 0;

    __syncthreads();

    // --- main loop: this wave's 64 ori tiles of 32 points (half of K) ---
    f32x16 acc = {INFINITY,INFINITY,INFINITY,INFINITY,
                  INFINITY,INFINITY,INFINITY,INFINITY,
                  INFINITY,INFINITY,INFINITY,INFINITY,
                  INFINITY,INFINITY,INFINITY,INFINITY};
    const f32x16 zc = {0,0,0,0, 0,0,0,0, 0,0,0,0, 0,0,0,0};
    const uint2* s2 = reinterpret_cast<const uint2*>(slds);   // 1 pt / uint2

    #pragma unroll 4
    for (int t = kh*64; t < kh*64 + 64; t += 2) {
        uint2 q0 = s2[t*32 + col];
        uint2 q1 = s2[(t+1)*32 + col];
        u32x4 w0 = {q0.x, q0.y, 0u, 0u};
        u32x4 w1 = {q1.x, q1.y, 0u, 0u};
        bf16x8 b0 = __builtin_bit_cast(bf16x8, w0);
        bf16x8 b1 = __builtin_bit_cast(bf16x8, w1);
        f32x16 c0 = __builtin_amdgcn_mfma_f32_32x32x16_bf16(afrag, b0, zc, 0,0,0);
        f32x16 c1 = __builtin_amdgcn_mfma_f32_32x32x16_bf16(afrag, b1, zc, 0,0,0);
        #pragma unroll
        for (int r = 0; r < 16; ++r)
            acc[r] = fminf(fminf(c0[r], c1[r]), acc[r]);   // v_min3_f32
    }

    // --- col-min (over ori dim) within each 32-lane half ---
    #pragma unroll
    for (int r = 0; r < 16; ++r) {
        float v = acc[r];
        v = fminf(v, __shfl_xor(v, 1));
        v = fminf(v, __shfl_xor(v, 2));
        v = fminf(v, __shfl_xor(v, 4));
        v = fminf(v, __shfl_xor(v, 8));
        v = fminf(v, __shfl_xor(v, 16));
        acc[r] = v;
    }
    if (col == 0) {   // lanes 0 and 32 publish 16 rows each
        #pragma unroll
        for (int r = 0; r < 16; ++r)
            rowmin[wid][(r&3) + 8*(r>>2) + 4*hi] = acc[r];
    }
    __syncthreads();

    // --- epilogue: combine K-halves, add a2; waves 2-3 fold obj-L2 ---
    float s = 0.f;
    if (wid < 2) {             // 128 threads: one adv row each
        int row = tid;         // 0..127
        int rg2 = row >> 5, ri = row & 31;
        float m = fminf(rowmin[rg2][ri], rowmin[4 + rg2][ri]);
        s = m + a2lds[row];
    } else if (wid < 4) {      // 96 of 128 threads: obj-L2 slice
        int li = (wid - 2)*64 + lane;
        if (li < OBJ_V4_PER_BLK) {
            int idx = b*OBJ_VEC4 + nseg*OBJ_V4_PER_BLK + li;
            float4 a = reinterpret_cast<const float4*>(adv_obj)[idx];
            float4 o = reinterpret_cast<const float4*>(ori_obj)[idx];
            float dx = a.x - o.x, dy = a.y - o.y, dz = a.z - o.z, dw = a.w - o.w;
            s = dx*dx + dy*dy + dz*dz + dw*dw;
        }
    }
    #pragma unroll
    for (int off = 32; off; off >>= 1) s += __shfl_down(s, off);
    if (lane == 0) {
        if (wid < 2)       red_c[wid]     = s;
        else if (wid < 4)  red_l[wid - 2] = s;
    }
    __syncthreads();
    if (tid == 0) csum[b*NSEG + nseg] = red_c[0] + red_c[1];
    if (tid == 1) lsq [b*NSEG + nseg] = red_l[0] + red_l[1];
}

__global__ __launch_bounds__(256) void final_kernel(
    const float* __restrict__ csum, const float* __restrict__ lsq,
    const float* __restrict__ w, float* __restrict__ out)
{
    const int tid = threadIdx.x;           // 256 threads, 2 partials each
    float c = csum[2*tid] + csum[2*tid + 1];
    float l = lsq [2*tid] + lsq [2*tid + 1];
    // 16 partial-pairs per batch live in one 16-lane group
    #pragma unroll
    for (int off = 8; off; off >>= 1) {
        c += __shfl_down(c, off, 16);
        l += __shfl_down(l, off, 16);
    }
    __shared__ float sc[B], sl[B];
    int bb = tid >> 4;
    if ((tid & 15) == 0) { sc[bb] = c; sl[bb] = l; }
    __syncthreads();
    if (tid < 64) {
        float cc = 0.f, ll = 0.f;
        if (tid < B) {
            float wt = w[tid];
            cc = (sc[tid] / (float)N) * wt;
            ll = sqrtf(sl[tid] + EPS_F) * wt;
        }
        #pragma unroll
        for (int off = 8; off; off >>= 1) {
            cc += __shfl_down(cc, off);
            ll += __shfl_down(ll, off);
        }
        if (tid == 0) out[0] = ll / (float)B + CD_W * (cc / (float)B);
    }
}

extern "C" void kernel_launch(void* const* d_in, const int* in_sizes, int n_in,
                              void* d_out, int out_size, void* d_ws, size_t ws_size,
                              hipStream_t stream)
{
    const float* adv_pc  = (const float*)d_in[0];
    const float* ori_pc  = (const float*)d_in[1];
    const float* adv_obj = (const float*)d_in[2];
    const float* ori_obj = (const float*)d_in[3];
    const float* weights = (const float*)d_in[4];
    float* out = (float*)d_out;
    float* ws  = (float*)d_ws;

    float* csum = ws + CS_OFF;
    float* lsq  = ws + LS_OFF;

    // 1) fused MFMA chamfer (in-block K-split, 8 waves) + obj-L2 partials:
    //    grid = (NSEG, B) = 512 blocks of 512
    chamfer_mfma_kernel<<<dim3(NSEG, B), dim3(BLK), 0, stream>>>(
        adv_pc, ori_pc, adv_obj, ori_obj, csum, lsq);

    // 2) weighted final combine (1 block)
    final_kernel<<<dim3(1), dim3(256), 0, stream>>>(csum, lsq, weights, out);
}